// Round 8
// baseline (163.146 us; speedup 1.0000x reference)
//
#include <hip/hip_runtime.h>

// TriangleAttentionStartingNode  (B=1, S=256, C=128, H=4, D=32)
//
// Pipeline:
//   K0 prep_w:  {wq,wk,wv,wg} -> wT split-bf16 [n=512][k=128] hi/lo (q-scale folded)
//   K1 lnproj:  z -> fused LN -> split-bf16 -> swizzled LDS -> MFMA
//               (A=W^T, B=zn^T, 3 split terms) -> LDS-TRANSPOSED epilogue:
//               4 phases (q,k,v,g); owning waves stage acc into LDS, all
//               threads store coalesced 16B lines:
//                 qt2: [jh][i][32hi|32lo]  kt2: [jh][k][32hi|32lo]
//                 vth/vtl: [jh][d][k=256]  gb: fp32 sigmoid [row][128]
//   K2 attn:    one block per (j,h); K/V in swizzled LDS; 16 waves x 16 q-rows;
//               swapped QK^T (split x3), in-register softmax, bpermute P
//               relayout (P-hi only), PV vs split V; gated write -> go
//   K3 out:     go @ wo -> d_out (fp32 tile GEMM)
//
// wb skipped: bias constant along softmax axis k -> cancels exactly.

#define NROWS 65536   // S*S

typedef unsigned short u16;
typedef unsigned int   u32;
typedef __attribute__((ext_vector_type(8))) short short8;
typedef __attribute__((ext_vector_type(4))) float f32x4;
typedef __attribute__((ext_vector_type(4))) u32   u32x4;
typedef __attribute__((ext_vector_type(4))) u16   u16x4;
typedef __attribute__((ext_vector_type(8))) u16   u16x8;   // 16 B

__device__ __forceinline__ u16 f2bf(float x) {            // fp32 -> bf16 RNE
    u32 u = __builtin_bit_cast(u32, x);
    return (u16)((u + 0x7fffu + ((u >> 16) & 1u)) >> 16);
}
__device__ __forceinline__ float bf2f(u16 h) {
    u32 u = (u32)h << 16;
    return __builtin_bit_cast(float, u);
}

// ------------------------------------------------- K0: weight transpose+split
__global__ __launch_bounds__(256) void prep_w(const float* __restrict__ wq,
                                              const float* __restrict__ wk,
                                              const float* __restrict__ wv,
                                              const float* __restrict__ wg,
                                              u16* __restrict__ wTh,
                                              u16* __restrict__ wTl)
{
    const int gid = blockIdx.x * 256 + threadIdx.x;   // 65536
    const int k = gid >> 9, n = gid & 511;
    const float* Wm = (n < 128) ? wq : (n < 256) ? wk : (n < 384) ? wv : wg;
    float f = Wm[k * 128 + (n & 127)];
    if (n < 128) f *= 0.17677669529663687f;           // 1/sqrt(D) into q
    const u16 h = f2bf(f);
    wTh[n * 128 + k] = h;
    wTl[n * 128 + k] = f2bf(f - bf2f(h));
}

// ------------------------------------------------- K1: fused LN + projection
// 512 blocks x 1024 threads (16 waves). Block owns 128 zn rows, all 512 outputs.
// Wave w>>2 owns matrix {0:q,1:k,2:v,3:g}; epilogue restages through LDS.
__global__ __launch_bounds__(1024) void lnproj_kernel(const float* __restrict__ z,
                                                      const float* __restrict__ lnw,
                                                      const float* __restrict__ lnb,
                                                      const u16* __restrict__ wTh,
                                                      const u16* __restrict__ wTl,
                                                      u16* __restrict__ qt2,
                                                      u16* __restrict__ kt2,
                                                      u16* __restrict__ vth,
                                                      u16* __restrict__ vtl,
                                                      float* __restrict__ gb)
{
    const int row0 = blockIdx.x * 128;
    const int tid  = threadIdx.x;

    __shared__ __align__(16) u16 S[32768];   // 64 KB, multi-purpose
    u16* Ah = S;            // [128 rows][16 slots of 8 u16], swizzled
    u16* Al = S + 16384;

    // ---- LN + split + stage (32 lanes per row, 4 iterations) ----
    {
        const int c4 = (tid & 31) * 4;                 // col, 0..124
        const float4 w4 = *(const float4*)(lnw + c4);
        const float4 b4 = *(const float4*)(lnb + c4);
        #pragma unroll
        for (int it = 0; it < 4; ++it) {
            const int row = it * 32 + (tid >> 5);
            const float4 v = *(const float4*)(z + (size_t)(row0 + row) * 128 + c4);
            float s  = v.x + v.y + v.z + v.w;
            float ss = v.x * v.x + v.y * v.y + v.z * v.z + v.w * v.w;
            #pragma unroll
            for (int off = 16; off > 0; off >>= 1) {
                s  += __shfl_xor(s,  off);
                ss += __shfl_xor(ss, off);
            }
            const float mu  = s * (1.0f / 128.0f);
            const float var = ss * (1.0f / 128.0f) - mu * mu;
            const float rs  = rsqrtf(var + 1e-5f);
            float o[4] = {(v.x - mu) * rs * w4.x + b4.x,
                          (v.y - mu) * rs * w4.y + b4.y,
                          (v.z - mu) * rs * w4.z + b4.z,
                          (v.w - mu) * rs * w4.w + b4.w};
            u16x4 hi, lo;
            #pragma unroll
            for (int c = 0; c < 4; ++c) {
                const u16 hx = f2bf(o[c]);
                hi[c] = hx;
                lo[c] = f2bf(o[c] - bf2f(hx));
            }
            const int slot = c4 >> 3, half = (c4 >> 2) & 1;
            const int phys = slot ^ (row & 15);
            *(u16x4*)&Ah[row * 128 + phys * 8 + half * 4] = hi;
            *(u16x4*)&Al[row * 128 + phys * 8 + half * 4] = lo;
        }
    }
    __syncthreads();

    // ---- MFMA: wave grid 8(n) x 2(m), wave tile 64x64 ----
    const int w    = tid >> 6;
    const int wn   = w >> 1, wm = w & 1;
    const int lane = tid & 63;
    const int g    = lane >> 4;
    const int qc   = lane & 15;

    f32x4 acc[4][4];   // [nt][mt]
    #pragma unroll
    for (int a = 0; a < 4; ++a)
        #pragma unroll
        for (int b = 0; b < 4; ++b) acc[a][b] = (f32x4){0.f, 0.f, 0.f, 0.f};

    #pragma unroll
    for (int kc = 0; kc < 4; ++kc) {
        short8 bh[4], bl[4];
        #pragma unroll
        for (int mt = 0; mt < 4; ++mt) {
            const int row  = wm * 64 + mt * 16 + qc;
            const int phys = (kc * 4 + g) ^ (row & 15);
            bh[mt] = *(const short8*)&Ah[row * 128 + phys * 8];
            bl[mt] = *(const short8*)&Al[row * 128 + phys * 8];
        }
        #pragma unroll
        for (int nt = 0; nt < 4; ++nt) {
            const int n_row = wn * 64 + nt * 16 + qc;
            const short8 ah = *(const short8*)(wTh + (size_t)n_row * 128 + kc * 32 + g * 8);
            const short8 al = *(const short8*)(wTl + (size_t)n_row * 128 + kc * 32 + g * 8);
            #pragma unroll
            for (int mt = 0; mt < 4; ++mt) {
                acc[nt][mt] = __builtin_amdgcn_mfma_f32_16x16x32_bf16(ah, bh[mt], acc[nt][mt], 0, 0, 0);
                acc[nt][mt] = __builtin_amdgcn_mfma_f32_16x16x32_bf16(ah, bl[mt], acc[nt][mt], 0, 0, 0);
                acc[nt][mt] = __builtin_amdgcn_mfma_f32_16x16x32_bf16(al, bh[mt], acc[nt][mt], 0, 0, 0);
            }
        }
    }
    __syncthreads();   // Ah/Al dead; S becomes staging buffer

    const int matw = w >> 2;          // matrix this wave owns
    const int wl   = wn & 1;          // n-half within matrix
    const int iblk = blockIdx.x >> 1;        // i (for q) / j (for k,v)
    const int base = (blockIdx.x & 1) * 128; // j-base (q) / kk-base (k,v)

    // ================= phase 0: q  (rows jh_local = m_local*4+h) =================
    if (matw == 0) {
        #pragma unroll
        for (int nt = 0; nt < 4; ++nt) {
            const int np = wl * 64 + nt * 16 + g * 4;
            const int h  = np >> 5, d0 = np & 31;
            const int sh = d0 >> 3, ins = d0 & 7;
            #pragma unroll
            for (int mt = 0; mt < 4; ++mt) {
                const int ml  = wm * 64 + mt * 16 + qc;
                const int row = ml * 4 + h;
                const int key = (row ^ (row >> 2)) & 7;
                const f32x4 a = acc[nt][mt];
                u16x4 hi, lo;
                #pragma unroll
                for (int c = 0; c < 4; ++c) {
                    const u16 hx = f2bf(a[c]);
                    hi[c] = hx;
                    lo[c] = f2bf(a[c] - bf2f(hx));
                }
                *(u16x4*)&S[row * 64 + ((sh    ) ^ key) * 8 + ins] = hi;
                *(u16x4*)&S[row * 64 + ((sh + 4) ^ key) * 8 + ins] = lo;
            }
        }
    }
    __syncthreads();
    #pragma unroll
    for (int it = 0; it < 4; ++it) {
        const int idx = it * 1024 + tid;
        const int row = idx >> 3, slot = idx & 7;
        const int key = (row ^ (row >> 2)) & 7;
        const u16x8 d = *(const u16x8*)&S[row * 64 + (slot ^ key) * 8];
        const int ml = row >> 2, h = row & 3;
        *(u16x8*)(qt2 + ((size_t)((base + ml) * 4 + h) * 256 + iblk) * 64 + slot * 8) = d;
    }
    __syncthreads();

    // ================= phase 1: k  (rows = h*128 + kk_local) =================
    if (matw == 1) {
        #pragma unroll
        for (int nt = 0; nt < 4; ++nt) {
            const int np = wl * 64 + nt * 16 + g * 4;
            const int h  = np >> 5, d0 = np & 31;
            const int sh = d0 >> 3, ins = d0 & 7;
            #pragma unroll
            for (int mt = 0; mt < 4; ++mt) {
                const int ml  = wm * 64 + mt * 16 + qc;
                const int row = h * 128 + ml;
                const int key = (row ^ (row >> 2)) & 7;
                const f32x4 a = acc[nt][mt];
                u16x4 hi, lo;
                #pragma unroll
                for (int c = 0; c < 4; ++c) {
                    const u16 hx = f2bf(a[c]);
                    hi[c] = hx;
                    lo[c] = f2bf(a[c] - bf2f(hx));
                }
                *(u16x4*)&S[row * 64 + ((sh    ) ^ key) * 8 + ins] = hi;
                *(u16x4*)&S[row * 64 + ((sh + 4) ^ key) * 8 + ins] = lo;
            }
        }
    }
    __syncthreads();
    #pragma unroll
    for (int it = 0; it < 4; ++it) {
        const int idx = it * 1024 + tid;
        const int row = idx >> 3, slot = idx & 7;
        const int key = (row ^ (row >> 2)) & 7;
        const u16x8 d = *(const u16x8*)&S[row * 64 + (slot ^ key) * 8];
        const int h = row >> 7, kk = row & 127;
        *(u16x8*)(kt2 + ((size_t)(iblk * 4 + h) * 256 + base + kk) * 64 + slot * 8) = d;
    }
    __syncthreads();

    // ================= phase 2: v  (hi then lo; rows = h*32+d, stride 136) ===
    #pragma unroll
    for (int sel = 0; sel < 2; ++sel) {
        if (matw == 2) {
            #pragma unroll
            for (int nt = 0; nt < 4; ++nt) {
                const int np = wl * 64 + nt * 16 + g * 4;
                const int h  = np >> 5, d0 = np & 31;
                #pragma unroll
                for (int mt = 0; mt < 4; ++mt) {
                    const int ml = wm * 64 + mt * 16 + qc;
                    const f32x4 a = acc[nt][mt];
                    #pragma unroll
                    for (int r = 0; r < 4; ++r) {
                        const u16 hx = f2bf(a[r]);
                        const u16 vv = sel ? f2bf(a[r] - bf2f(hx)) : hx;
                        S[(h * 32 + d0 + r) * 136 + ml] = vv;
                    }
                }
            }
        }
        __syncthreads();
        u16* dstm = sel ? vtl : vth;
        #pragma unroll
        for (int it = 0; it < 2; ++it) {
            const int idx = it * 1024 + tid;          // 2048 chunks of 16B
            const int row = idx >> 4, chunk = idx & 15;
            const u16x8 d = *(const u16x8*)&S[row * 136 + chunk * 8];
            const int h = row >> 5, dd = row & 31;
            *(u16x8*)(dstm + ((size_t)(iblk * 4 + h) * 32 + dd) * 256 + base + chunk * 8) = d;
        }
        __syncthreads();
    }

    // ================= phase 3: g  (float [128][128], sigmoid at stage) ======
    {
        float* F = (float*)S;
        if (matw == 3) {
            #pragma unroll
            for (int nt = 0; nt < 4; ++nt) {
                const int np = wl * 64 + nt * 16 + g * 4;   // nn 0..124
                #pragma unroll
                for (int mt = 0; mt < 4; ++mt) {
                    const int ml  = wm * 64 + mt * 16 + qc;
                    const int key = (ml ^ (ml >> 2)) & 7;
                    const f32x4 a = acc[nt][mt];
                    float4 sg;
                    sg.x = 1.0f / (1.0f + __expf(-a[0]));
                    sg.y = 1.0f / (1.0f + __expf(-a[1]));
                    sg.z = 1.0f / (1.0f + __expf(-a[2]));
                    sg.w = 1.0f / (1.0f + __expf(-a[3]));
                    *(float4*)&F[ml * 128 + (((np >> 2) ^ key)) * 4] = sg;
                }
            }
        }
        __syncthreads();
        #pragma unroll
        for (int it = 0; it < 4; ++it) {
            const int idx = it * 1024 + tid;          // 4096 float4
            const int row = idx >> 5, slot = idx & 31;
            const int key = (row ^ (row >> 2)) & 7;
            const float4 d = *(const float4*)&F[row * 128 + (slot ^ key) * 4];
            *(float4*)(gb + (size_t)(row0 + row) * 128 + slot * 4) = d;
        }
    }
}

// ---------------------------------------------------------- K2: MFMA attention
__global__ __launch_bounds__(1024) void attn_kernel(const u16* __restrict__ qt2,
                                                    const u16* __restrict__ kt2,
                                                    const u16* __restrict__ vth,
                                                    const u16* __restrict__ vtl,
                                                    const float* __restrict__ gb,
                                                    float* __restrict__ go)
{
    const int jh   = blockIdx.x;
    const int tid  = threadIdx.x;
    const int q0   = (tid >> 6) * 16;          // wave id * 16
    const int lane = tid & 63;
    const int g    = lane >> 4;
    const int qc   = lane & 15;

    __shared__ u16 Ks[16384];    // 32 KB: [256 rows][8 slots x 8 u16], swizzled
    __shared__ u16 Vs[16384];    // 32 KB: vth [32][32 slots] then vtl, swizzled

    {
        const u16* kg = kt2 + (size_t)jh * 16384;
        #pragma unroll
        for (int it = 0; it < 2; ++it) {
            const int t   = it * 1024 + tid;
            const int row = t >> 3, c = t & 7;
            const int dc  = c ^ (row & 7);
            *(u16x8*)&Ks[row * 64 + dc * 8] = *(const u16x8*)(kg + t * 8);
        }
        const u16* vhg = vth + (size_t)jh * 8192;
        const u16* vlg = vtl + (size_t)jh * 8192;
        {
            const int t   = tid;
            const int row = t >> 5, c = t & 31;
            const int dc  = (c & 24) | ((c & 7) ^ (row & 7));
            *(u16x8*)&Vs[row * 256 + dc * 8] = *(const u16x8*)(vhg + t * 8);
        }
        {
            const int t   = tid;
            const int row = t >> 5, c = t & 31;
            const int dc  = (c & 24) | ((c & 7) ^ (row & 7));
            *(u16x8*)&Vs[8192 + row * 256 + dc * 8] = *(const u16x8*)(vlg + t * 8);
        }
    }

    const u16* qrow = qt2 + ((size_t)jh * 256 + q0 + qc) * 64;
    const short8 bqh = *(const short8*)(qrow + g * 8);
    const short8 bql = *(const short8*)(qrow + 32 + g * 8);

    __syncthreads();

    f32x4 st[16];
    #pragma unroll
    for (int t = 0; t < 16; ++t) st[t] = (f32x4){0.f, 0.f, 0.f, 0.f};

    const int slotH = (g ^ (qc & 7)) * 8;
    #pragma unroll
    for (int kt = 0; kt < 16; ++kt) {
        const int rbase = (kt * 16 + qc) * 64;
        const short8 ah = *(const short8*)&Ks[rbase + slotH];
        const short8 al = *(const short8*)&Ks[rbase + (slotH ^ 32)];
        st[kt] = __builtin_amdgcn_mfma_f32_16x16x32_bf16(ah, bqh, st[kt], 0, 0, 0);
        st[kt] = __builtin_amdgcn_mfma_f32_16x16x32_bf16(ah, bql, st[kt], 0, 0, 0);
        st[kt] = __builtin_amdgcn_mfma_f32_16x16x32_bf16(al, bqh, st[kt], 0, 0, 0);
    }

    float m = -1e30f;
    #pragma unroll
    for (int t = 0; t < 16; ++t)
        #pragma unroll
        for (int r = 0; r < 4; ++r) m = fmaxf(m, st[t][r]);
    m = fmaxf(m, __shfl_xor(m, 16));
    m = fmaxf(m, __shfl_xor(m, 32));

    float l = 0.0f;
    #pragma unroll
    for (int t = 0; t < 16; ++t)
        #pragma unroll
        for (int r = 0; r < 4; ++r) {
            const float p = __expf(st[t][r] - m);
            st[t][r] = p;
            l += p;
        }
    l += __shfl_xor(l, 16);
    l += __shfl_xor(l, 32);
    const float inv = 1.0f / l;
    #pragma unroll
    for (int t = 0; t < 16; ++t)
        #pragma unroll
        for (int r = 0; r < 4; ++r) st[t][r] *= inv;

    f32x4 o0 = (f32x4){0.f, 0.f, 0.f, 0.f};
    f32x4 o1 = (f32x4){0.f, 0.f, 0.f, 0.f};
    const int  slA   = qc + 16 * (2 * (g & 1));
    const int  slB   = slA + 16;
    const bool upper = (g >> 1) != 0;

    #pragma unroll
    for (int kc = 0; kc < 8; ++kc) {
        u32 pkh[2][2];
        #pragma unroll
        for (int tt = 0; tt < 2; ++tt)
            #pragma unroll
            for (int u = 0; u < 2; ++u) {
                const float x = st[2 * kc + tt][2 * u];
                const float y = st[2 * kc + tt][2 * u + 1];
                pkh[tt][u] = (u32)f2bf(x) | ((u32)f2bf(y) << 16);
            }
        u32x4 AH;
        #pragma unroll
        for (int j = 0; j < 4; ++j) {
            const int u  = j & 1;
            const int sl = (j < 2) ? slA : slB;
            const u32 h0 = (u32)__shfl((int)pkh[0][u], sl);
            const u32 h1 = (u32)__shfl((int)pkh[1][u], sl);
            AH[j] = upper ? h1 : h0;
        }
        const short8 pah = __builtin_bit_cast(short8, AH);

        const int vc    = (((kc & 1) * 4 + g) ^ (qc & 7));
        const int vslot = ((kc >> 1) * 8 + vc) * 8;
        const short8 b0h = *(const short8*)&Vs[        qc * 256 + vslot];
        const short8 b0l = *(const short8*)&Vs[8192 +  qc * 256 + vslot];
        const short8 b1h = *(const short8*)&Vs[       (16 + qc) * 256 + vslot];
        const short8 b1l = *(const short8*)&Vs[8192 + (16 + qc) * 256 + vslot];
        o0 = __builtin_amdgcn_mfma_f32_16x16x32_bf16(pah, b0h, o0, 0, 0, 0);
        o0 = __builtin_amdgcn_mfma_f32_16x16x32_bf16(pah, b0l, o0, 0, 0, 0);
        o1 = __builtin_amdgcn_mfma_f32_16x16x32_bf16(pah, b1h, o1, 0, 0, 0);
        o1 = __builtin_amdgcn_mfma_f32_16x16x32_bf16(pah, b1l, o1, 0, 0, 0);
    }

    const int jj = jh >> 2, h = jh & 3;
    #pragma unroll
    for (int r = 0; r < 4; ++r) {
        const int qg = q0 + g * 4 + r;
        const size_t base = ((size_t)qg * 256 + jj) * 128 + h * 32 + qc;
        go[base]      = gb[base]      * o0[r];
        go[base + 16] = gb[base + 16] * o1[r];
    }
}

// ------------------------------------------------------- K3: output GEMM
__global__ __launch_bounds__(256) void out_kernel(const float* __restrict__ A,
                                                  const float* __restrict__ W,
                                                  float* __restrict__ out)
{
    const int by   = blockIdx.x;
    const int row0 = by * 128;

    __shared__ float As[32][132];
    __shared__ float Bs[32][132];

    const int tid = threadIdx.x;
    const int tm  = tid & 15, tn = tid >> 4;
    const int m0  = tm * 4,  n0 = tn * 4;

    float acc[8][8];
    #pragma unroll
    for (int a = 0; a < 8; ++a)
        #pragma unroll
        for (int q = 0; q < 8; ++q) acc[a][q] = 0.0f;

    for (int kc = 0; kc < 128; kc += 32) {
        __syncthreads();
        #pragma unroll
        for (int it = 0; it < 4; ++it) {
            const int id = it * 256 + tid;
            const int m  = id >> 3;
            const int kq = (id & 7) * 4;
            const float4 a4 = *(const float4*)(A + (size_t)(row0 + m) * 128 + kc + kq);
            As[kq + 0][m] = a4.x; As[kq + 1][m] = a4.y;
            As[kq + 2][m] = a4.z; As[kq + 3][m] = a4.w;
        }
        #pragma unroll
        for (int it = 0; it < 4; ++it) {
            const int id = it * 256 + tid;
            const int kk = id >> 5;
            const int c4 = (id & 31) * 4;
            *(float4*)&Bs[kk][c4] = *(const float4*)(W + (size_t)(kc + kk) * 128 + c4);
        }
        __syncthreads();
        #pragma unroll
        for (int k = 0; k < 32; ++k) {
            const float4 a0 = *(const float4*)&As[k][m0];
            const float4 a1 = *(const float4*)&As[k][m0 + 64];
            const float4 b0 = *(const float4*)&Bs[k][n0];
            const float4 b1 = *(const float4*)&Bs[k][n0 + 64];
            const float av[8] = {a0.x, a0.y, a0.z, a0.w, a1.x, a1.y, a1.z, a1.w};
            const float bv[8] = {b0.x, b0.y, b0.z, b0.w, b1.x, b1.y, b1.z, b1.w};
            #pragma unroll
            for (int ii = 0; ii < 8; ++ii)
                #pragma unroll
                for (int jj = 0; jj < 8; ++jj)
                    acc[ii][jj] += av[ii] * bv[jj];
        }
    }

    #pragma unroll
    for (int ii = 0; ii < 8; ++ii) {
        const int mA = (ii < 4) ? (m0 + ii) : (m0 + 60 + ii);
        const int r  = row0 + mA;
        #pragma unroll
        for (int nh = 0; nh < 2; ++nh) {
            const int c0 = n0 + nh * 64;
            float4 vv;
            vv.x = acc[ii][nh * 4 + 0]; vv.y = acc[ii][nh * 4 + 1];
            vv.z = acc[ii][nh * 4 + 2]; vv.w = acc[ii][nh * 4 + 3];
            *(float4*)(out + (size_t)r * 128 + c0) = vv;
        }
    }
}

// ----------------------------------------------------------------- launch
extern "C" void kernel_launch(void* const* d_in, const int* in_sizes, int n_in,
                              void* d_out, int out_size, void* d_ws, size_t ws_size,
                              hipStream_t stream)
{
    const float* z   = (const float*)d_in[0];
    const float* lnw = (const float*)d_in[1];
    const float* lnb = (const float*)d_in[2];
    const float* wq  = (const float*)d_in[3];
    const float* wk  = (const float*)d_in[4];
    const float* wv  = (const float*)d_in[5];
    // d_in[6] = wb : unused (constant along softmax axis -> cancels)
    const float* wg  = (const float*)d_in[7];
    const float* wo  = (const float*)d_in[8];

    const size_t T = (size_t)NROWS * 128;       // 8,388,608 elements
    float* go  = (float*)d_ws;                  // also hosts wT (liveness disjoint)
    u16*   wTh = (u16*)d_ws;
    u16*   wTl = wTh + 512 * 128;
    float* gb  = (float*)d_ws + T;
    u16*   qt2 = (u16*)(gb + T);
    u16*   kt2 = qt2 + 2 * T;
    u16*   vth = kt2 + 2 * T;
    u16*   vtl = vth + T;

    prep_w       <<<256,          256, 0, stream>>>(wq, wk, wv, wg, wTh, wTl);
    lnproj_kernel<<<512,         1024, 0, stream>>>(z, lnw, lnb, wTh, wTl,
                                                    qt2, kt2, vth, vtl, gb);
    attn_kernel  <<<1024,        1024, 0, stream>>>(qt2, kt2, vth, vtl, gb, go);
    out_kernel   <<<512,          256, 0, stream>>>(go, wo, (float*)d_out);
}

// Round 10
// 156.809 us; speedup vs baseline: 1.0404x; 1.0404x over previous
//
#include <hip/hip_runtime.h>

// TriangleAttentionStartingNode  (B=1, S=256, C=128, H=4, D=32)
//
// Pipeline:
//   K0 prep_w:  {wq,wk,wv,wg} -> wT split-bf16 [n=512][k=128] hi/lo (q-scale folded)
//   K1 lnproj:  512 thr, block = 64 rows x 512 cols. Fused LN -> split-bf16 ->
//               swizzled LDS -> MFMA (A=W^T, B=zn^T, 3 split terms) -> direct
//               scatter epilogue:
//                 qt2: [jh][i][32hi|32lo]  kt2: [jh][k][32hi|32lo]
//                 vth/vtl: [jh][d][k=256]  gb: fp32 sigmoid [row][128]
//   K2 attn:    512 thr = 8 waves x 16 q-rows; 2 blocks per (j,h); K/V in
//               swizzled LDS; swapped QK^T (split x3), in-register softmax,
//               bpermute P relayout (P-hi only), PV vs split V; gated -> go
//   K3 out:     go @ wo -> d_out (fp32 tile GEMM)
//
// wb skipped: bias constant along softmax axis k -> cancels exactly.
// Round-8 lesson: __launch_bounds__(1024) caps VGPR at 64 -> acc spills to
// scratch (~35 MB phantom WRITE_SIZE). 512-thread blocks lift the cap.

#define NROWS 65536   // S*S

typedef unsigned short u16;
typedef unsigned int   u32;
typedef __attribute__((ext_vector_type(8))) short short8;
typedef __attribute__((ext_vector_type(4))) float f32x4;
typedef __attribute__((ext_vector_type(4))) u32   u32x4;
typedef __attribute__((ext_vector_type(4))) u16   u16x4;
typedef __attribute__((ext_vector_type(8))) u16   u16x8;   // 16 B

__device__ __forceinline__ u16 f2bf(float x) {            // fp32 -> bf16 RNE
    u32 u = __builtin_bit_cast(u32, x);
    return (u16)((u + 0x7fffu + ((u >> 16) & 1u)) >> 16);
}
__device__ __forceinline__ float bf2f(u16 h) {
    u32 u = (u32)h << 16;
    return __builtin_bit_cast(float, u);
}

// ------------------------------------------------- K0: weight transpose+split
__global__ __launch_bounds__(256) void prep_w(const float* __restrict__ wq,
                                              const float* __restrict__ wk,
                                              const float* __restrict__ wv,
                                              const float* __restrict__ wg,
                                              u16* __restrict__ wTh,
                                              u16* __restrict__ wTl)
{
    const int gid = blockIdx.x * 256 + threadIdx.x;   // 65536
    const int k = gid >> 9, n = gid & 511;
    const float* Wm = (n < 128) ? wq : (n < 256) ? wk : (n < 384) ? wv : wg;
    float f = Wm[k * 128 + (n & 127)];
    if (n < 128) f *= 0.17677669529663687f;           // 1/sqrt(D) into q
    const u16 h = f2bf(f);
    wTh[n * 128 + k] = h;
    wTl[n * 128 + k] = f2bf(f - bf2f(h));
}

// ------------------------------------------------- K1: fused LN + projection
// 1024 blocks x 512 threads (8 waves). Block owns 64 zn rows, all 512 outputs.
// Wave w covers n in [w*64, w*64+64); matrix = w>>1 (wave-uniform).
__global__ __launch_bounds__(512) void lnproj_kernel(const float* __restrict__ z,
                                                     const float* __restrict__ lnw,
                                                     const float* __restrict__ lnb,
                                                     const u16* __restrict__ wTh,
                                                     const u16* __restrict__ wTl,
                                                     u16* __restrict__ qt2,
                                                     u16* __restrict__ kt2,
                                                     u16* __restrict__ vth,
                                                     u16* __restrict__ vtl,
                                                     float* __restrict__ gb)
{
    const int row0 = blockIdx.x * 64;
    const int tid  = threadIdx.x;

    __shared__ __align__(16) u16 Ah[8192];   // 16 KB: [64 rows][16 slots x 8 u16]
    __shared__ __align__(16) u16 Al[8192];

    // ---- LN + split + stage (32 lanes per row; 16 rows/pass x 4) ----
    {
        const int c4 = (tid & 31) * 4;                 // col, 0..124
        const float4 w4 = *(const float4*)(lnw + c4);
        const float4 b4 = *(const float4*)(lnb + c4);
        #pragma unroll
        for (int it = 0; it < 4; ++it) {
            const int row = it * 16 + (tid >> 5);
            const float4 v = *(const float4*)(z + (size_t)(row0 + row) * 128 + c4);
            float s  = v.x + v.y + v.z + v.w;
            float ss = v.x * v.x + v.y * v.y + v.z * v.z + v.w * v.w;
            #pragma unroll
            for (int off = 16; off > 0; off >>= 1) {
                s  += __shfl_xor(s,  off);
                ss += __shfl_xor(ss, off);
            }
            const float mu  = s * (1.0f / 128.0f);
            const float var = ss * (1.0f / 128.0f) - mu * mu;
            const float rs  = rsqrtf(var + 1e-5f);
            float o[4] = {(v.x - mu) * rs * w4.x + b4.x,
                          (v.y - mu) * rs * w4.y + b4.y,
                          (v.z - mu) * rs * w4.z + b4.z,
                          (v.w - mu) * rs * w4.w + b4.w};
            u16x4 hi, lo;
            #pragma unroll
            for (int c = 0; c < 4; ++c) {
                const u16 hx = f2bf(o[c]);
                hi[c] = hx;
                lo[c] = f2bf(o[c] - bf2f(hx));
            }
            const int slot = c4 >> 3, half = (c4 >> 2) & 1;
            const int phys = slot ^ (row & 15);
            *(u16x4*)&Ah[row * 128 + phys * 8 + half * 4] = hi;
            *(u16x4*)&Al[row * 128 + phys * 8 + half * 4] = lo;
        }
    }
    __syncthreads();

    // ---- MFMA: 8 waves, wave tile 64(n) x 64(m) ----
    const int w    = tid >> 6;          // n-tile group, 0..7
    const int lane = tid & 63;
    const int g    = lane >> 4;
    const int qc   = lane & 15;

    f32x4 acc[4][4];   // [nt][mt]
    #pragma unroll
    for (int a = 0; a < 4; ++a)
        #pragma unroll
        for (int b = 0; b < 4; ++b) acc[a][b] = (f32x4){0.f, 0.f, 0.f, 0.f};

    #pragma unroll
    for (int kc = 0; kc < 4; ++kc) {
        short8 bh[4], bl[4];
        #pragma unroll
        for (int mt = 0; mt < 4; ++mt) {
            const int row  = mt * 16 + qc;
            const int phys = (kc * 4 + g) ^ (row & 15);
            bh[mt] = *(const short8*)&Ah[row * 128 + phys * 8];
            bl[mt] = *(const short8*)&Al[row * 128 + phys * 8];
        }
        #pragma unroll
        for (int nt = 0; nt < 4; ++nt) {
            const int n_row = w * 64 + nt * 16 + qc;
            const short8 ah = *(const short8*)(wTh + (size_t)n_row * 128 + kc * 32 + g * 8);
            const short8 al = *(const short8*)(wTl + (size_t)n_row * 128 + kc * 32 + g * 8);
            #pragma unroll
            for (int mt = 0; mt < 4; ++mt) {
                acc[nt][mt] = __builtin_amdgcn_mfma_f32_16x16x32_bf16(ah, bh[mt], acc[nt][mt], 0, 0, 0);
                acc[nt][mt] = __builtin_amdgcn_mfma_f32_16x16x32_bf16(ah, bl[mt], acc[nt][mt], 0, 0, 0);
                acc[nt][mt] = __builtin_amdgcn_mfma_f32_16x16x32_bf16(al, bh[mt], acc[nt][mt], 0, 0, 0);
            }
        }
    }

    // ---- epilogue: lane holds 4 consecutive n for one m; direct scatter ----
    #pragma unroll
    for (int nt = 0; nt < 4; ++nt) {
        const int nb  = w * 64 + nt * 16 + g * 4;      // 0..508
        const int mat = nb >> 7;                       // 0..3 (wave-uniform)
        const int nn  = nb & 127;
        const int h   = nn >> 5, d0 = nn & 31;
        #pragma unroll
        for (int mt = 0; mt < 4; ++mt) {
            const int m = row0 + mt * 16 + qc;         // global zn row
            const f32x4 a = acc[nt][mt];
            if (mat == 3) {
                float4 sg;
                sg.x = 1.0f / (1.0f + __expf(-a[0]));
                sg.y = 1.0f / (1.0f + __expf(-a[1]));
                sg.z = 1.0f / (1.0f + __expf(-a[2]));
                sg.w = 1.0f / (1.0f + __expf(-a[3]));
                *(float4*)(gb + (size_t)m * 128 + nn) = sg;
            } else if (mat == 2) {
                const int j = m >> 8, kk = m & 255;
                #pragma unroll
                for (int r = 0; r < 4; ++r) {
                    const u16 hx = f2bf(a[r]);
                    const size_t idx = ((size_t)(j * 4 + h) * 32 + d0 + r) * 256 + kk;
                    vth[idx] = hx;
                    vtl[idx] = f2bf(a[r] - bf2f(hx));
                }
            } else {
                u16x4 hi, lo;
                #pragma unroll
                for (int c = 0; c < 4; ++c) {
                    const u16 hx = f2bf(a[c]);
                    hi[c] = hx;
                    lo[c] = f2bf(a[c] - bf2f(hx));
                }
                u16* dst;
                if (mat == 0) {
                    const int i = m >> 8, j = m & 255;
                    dst = qt2 + ((size_t)(j * 4 + h) * 256 + i) * 64 + d0;
                } else {
                    const int j = m >> 8, kk = m & 255;
                    dst = kt2 + ((size_t)(j * 4 + h) * 256 + kk) * 64 + d0;
                }
                *(u16x4*)dst        = hi;
                *(u16x4*)(dst + 32) = lo;
            }
        }
    }
}

// ---------------------------------------------------------- K2: MFMA attention
// Grid 2048: block = (jh, i-half). 512 threads = 8 waves x 16 q-rows.
// K (split, [256][64] u16) and V (hi+lo, [32][256] u16 each) staged into LDS
// with XOR swizzle (16B slot ^= row&7). Swapped QK^T: lane (g,qc) holds score
// column q=qc, keys g*4+r+16t. PV uses P-hi only.
__global__ __launch_bounds__(512) void attn_kernel(const u16* __restrict__ qt2,
                                                   const u16* __restrict__ kt2,
                                                   const u16* __restrict__ vth,
                                                   const u16* __restrict__ vtl,
                                                   const float* __restrict__ gb,
                                                   float* __restrict__ go)
{
    const int blk  = blockIdx.x;
    const int jh   = blk >> 1;
    const int tid  = threadIdx.x;
    const int q0   = (blk & 1) * 128 + (tid >> 6) * 16;
    const int lane = tid & 63;
    const int g    = lane >> 4;
    const int qc   = lane & 15;

    __shared__ u16 Ks[16384];    // 32 KB: [256 rows][8 slots x 8 u16], swizzled
    __shared__ u16 Vs[16384];    // 32 KB: vth [32][32 slots] then vtl, swizzled

    // ---- stage K/V into LDS (16B chunks, swizzle on write) ----
    {
        const u16* kg = kt2 + (size_t)jh * 16384;
        #pragma unroll
        for (int it = 0; it < 4; ++it) {
            const int t   = it * 512 + tid;         // 2048 chunks of 8 u16
            const int row = t >> 3, c = t & 7;
            const int dc  = c ^ (row & 7);
            *(u16x8*)&Ks[row * 64 + dc * 8] = *(const u16x8*)(kg + t * 8);
        }
        const u16* vhg = vth + (size_t)jh * 8192;
        const u16* vlg = vtl + (size_t)jh * 8192;
        #pragma unroll
        for (int it = 0; it < 2; ++it) {
            const int t   = it * 512 + tid;         // 1024 chunks
            const int row = t >> 5, c = t & 31;
            const int dc  = (c & 24) | ((c & 7) ^ (row & 7));
            *(u16x8*)&Vs[row * 256 + dc * 8] = *(const u16x8*)(vhg + t * 8);
        }
        #pragma unroll
        for (int it = 0; it < 2; ++it) {
            const int t   = it * 512 + tid;
            const int row = t >> 5, c = t & 31;
            const int dc  = (c & 24) | ((c & 7) ^ (row & 7));
            *(u16x8*)&Vs[8192 + row * 256 + dc * 8] = *(const u16x8*)(vlg + t * 8);
        }
    }

    // Q B-fragments from global (coalesced)
    const u16* qrow = qt2 + ((size_t)jh * 256 + q0 + qc) * 64;
    const short8 bqh = *(const short8*)(qrow + g * 8);
    const short8 bql = *(const short8*)(qrow + 32 + g * 8);

    __syncthreads();

    // ---- QK^T: 16 key-tiles x 3 split terms, K from swizzled LDS ----
    f32x4 st[16];
    #pragma unroll
    for (int t = 0; t < 16; ++t) st[t] = (f32x4){0.f, 0.f, 0.f, 0.f};

    const int slotH = (g ^ (qc & 7)) * 8;
    #pragma unroll
    for (int kt = 0; kt < 16; ++kt) {
        const int rbase = (kt * 16 + qc) * 64;
        const short8 ah = *(const short8*)&Ks[rbase + slotH];
        const short8 al = *(const short8*)&Ks[rbase + (slotH ^ 32)];
        st[kt] = __builtin_amdgcn_mfma_f32_16x16x32_bf16(ah, bqh, st[kt], 0, 0, 0);
        st[kt] = __builtin_amdgcn_mfma_f32_16x16x32_bf16(ah, bql, st[kt], 0, 0, 0);
        st[kt] = __builtin_amdgcn_mfma_f32_16x16x32_bf16(al, bqh, st[kt], 0, 0, 0);
    }

    // ---- softmax over 256 keys for q = qc ----
    float m = -1e30f;
    #pragma unroll
    for (int t = 0; t < 16; ++t)
        #pragma unroll
        for (int r = 0; r < 4; ++r) m = fmaxf(m, st[t][r]);
    m = fmaxf(m, __shfl_xor(m, 16));
    m = fmaxf(m, __shfl_xor(m, 32));

    float l = 0.0f;
    #pragma unroll
    for (int t = 0; t < 16; ++t)
        #pragma unroll
        for (int r = 0; r < 4; ++r) {
            const float p = __expf(st[t][r] - m);
            st[t][r] = p;
            l += p;
        }
    l += __shfl_xor(l, 16);
    l += __shfl_xor(l, 32);
    const float inv = 1.0f / l;
    #pragma unroll
    for (int t = 0; t < 16; ++t)
        #pragma unroll
        for (int r = 0; r < 4; ++r) st[t][r] *= inv;

    // ---- PV: P-hi relayout via shfl, V (hi+lo) from swizzled LDS ----
    f32x4 o0 = (f32x4){0.f, 0.f, 0.f, 0.f};
    f32x4 o1 = (f32x4){0.f, 0.f, 0.f, 0.f};
    const int  slA   = qc + 16 * (2 * (g & 1));
    const int  slB   = slA + 16;
    const bool upper = (g >> 1) != 0;

    #pragma unroll
    for (int kc = 0; kc < 8; ++kc) {
        u32 pkh[2][2];
        #pragma unroll
        for (int tt = 0; tt < 2; ++tt)
            #pragma unroll
            for (int u = 0; u < 2; ++u) {
                const float x = st[2 * kc + tt][2 * u];
                const float y = st[2 * kc + tt][2 * u + 1];
                pkh[tt][u] = (u32)f2bf(x) | ((u32)f2bf(y) << 16);
            }
        u32x4 AH;
        #pragma unroll
        for (int j = 0; j < 4; ++j) {
            const int u  = j & 1;
            const int sl = (j < 2) ? slA : slB;
            const u32 h0 = (u32)__shfl((int)pkh[0][u], sl);
            const u32 h1 = (u32)__shfl((int)pkh[1][u], sl);
            AH[j] = upper ? h1 : h0;
        }
        const short8 pah = __builtin_bit_cast(short8, AH);

        const int vc    = (((kc & 1) * 4 + g) ^ (qc & 7));
        const int vslot = ((kc >> 1) * 8 + vc) * 8;
        const short8 b0h = *(const short8*)&Vs[        qc * 256 + vslot];
        const short8 b0l = *(const short8*)&Vs[8192 +  qc * 256 + vslot];
        const short8 b1h = *(const short8*)&Vs[       (16 + qc) * 256 + vslot];
        const short8 b1l = *(const short8*)&Vs[8192 + (16 + qc) * 256 + vslot];
        o0 = __builtin_amdgcn_mfma_f32_16x16x32_bf16(pah, b0h, o0, 0, 0, 0);
        o0 = __builtin_amdgcn_mfma_f32_16x16x32_bf16(pah, b0l, o0, 0, 0, 0);
        o1 = __builtin_amdgcn_mfma_f32_16x16x32_bf16(pah, b1h, o1, 0, 0, 0);
        o1 = __builtin_amdgcn_mfma_f32_16x16x32_bf16(pah, b1l, o1, 0, 0, 0);
    }

    // ---- epilogue: gate and store ----
    const int jj = jh >> 2, h = jh & 3;
    #pragma unroll
    for (int r = 0; r < 4; ++r) {
        const int qg = q0 + g * 4 + r;
        const size_t base = ((size_t)qg * 256 + jj) * 128 + h * 32 + qc;
        go[base]      = gb[base]      * o0[r];
        go[base + 16] = gb[base + 16] * o1[r];
    }
}

// ------------------------------------------------------- K3: output GEMM
__global__ __launch_bounds__(256) void out_kernel(const float* __restrict__ A,
                                                  const float* __restrict__ W,
                                                  float* __restrict__ out)
{
    const int by   = blockIdx.x;
    const int row0 = by * 128;

    __shared__ float As[32][132];
    __shared__ float Bs[32][132];

    const int tid = threadIdx.x;
    const int tm  = tid & 15, tn = tid >> 4;
    const int m0  = tm * 4,  n0 = tn * 4;

    float acc[8][8];
    #pragma unroll
    for (int a = 0; a < 8; ++a)
        #pragma unroll
        for (int q = 0; q < 8; ++q) acc[a][q] = 0.0f;

    for (int kc = 0; kc < 128; kc += 32) {
        __syncthreads();
        #pragma unroll
        for (int it = 0; it < 4; ++it) {
            const int id = it * 256 + tid;
            const int m  = id >> 3;
            const int kq = (id & 7) * 4;
            const float4 a4 = *(const float4*)(A + (size_t)(row0 + m) * 128 + kc + kq);
            As[kq + 0][m] = a4.x; As[kq + 1][m] = a4.y;
            As[kq + 2][m] = a4.z; As[kq + 3][m] = a4.w;
        }
        #pragma unroll
        for (int it = 0; it < 4; ++it) {
            const int id = it * 256 + tid;
            const int kk = id >> 5;
            const int c4 = (id & 31) * 4;
            *(float4*)&Bs[kk][c4] = *(const float4*)(W + (size_t)(kc + kk) * 128 + c4);
        }
        __syncthreads();
        #pragma unroll
        for (int k = 0; k < 32; ++k) {
            const float4 a0 = *(const float4*)&As[k][m0];
            const float4 a1 = *(const float4*)&As[k][m0 + 64];
            const float4 b0 = *(const float4*)&Bs[k][n0];
            const float4 b1 = *(const float4*)&Bs[k][n0 + 64];
            const float av[8] = {a0.x, a0.y, a0.z, a0.w, a1.x, a1.y, a1.z, a1.w};
            const float bv[8] = {b0.x, b0.y, b0.z, b0.w, b1.x, b1.y, b1.z, b1.w};
            #pragma unroll
            for (int ii = 0; ii < 8; ++ii)
                #pragma unroll
                for (int jj = 0; jj < 8; ++jj)
                    acc[ii][jj] += av[ii] * bv[jj];
        }
    }

    #pragma unroll
    for (int ii = 0; ii < 8; ++ii) {
        const int mA = (ii < 4) ? (m0 + ii) : (m0 + 60 + ii);
        const int r  = row0 + mA;
        #pragma unroll
        for (int nh = 0; nh < 2; ++nh) {
            const int c0 = n0 + nh * 64;
            float4 vv;
            vv.x = acc[ii][nh * 4 + 0]; vv.y = acc[ii][nh * 4 + 1];
            vv.z = acc[ii][nh * 4 + 2]; vv.w = acc[ii][nh * 4 + 3];
            *(float4*)(out + (size_t)r * 128 + c0) = vv;
        }
    }
}

// ----------------------------------------------------------------- launch
extern "C" void kernel_launch(void* const* d_in, const int* in_sizes, int n_in,
                              void* d_out, int out_size, void* d_ws, size_t ws_size,
                              hipStream_t stream)
{
    const float* z   = (const float*)d_in[0];
    const float* lnw = (const float*)d_in[1];
    const float* lnb = (const float*)d_in[2];
    const float* wq  = (const float*)d_in[3];
    const float* wk  = (const float*)d_in[4];
    const float* wv  = (const float*)d_in[5];
    // d_in[6] = wb : unused (constant along softmax axis -> cancels)
    const float* wg  = (const float*)d_in[7];
    const float* wo  = (const float*)d_in[8];

    const size_t T = (size_t)NROWS * 128;       // 8,388,608 elements
    float* go  = (float*)d_ws;                  // also hosts wT (liveness disjoint)
    u16*   wTh = (u16*)d_ws;
    u16*   wTl = wTh + 512 * 128;
    float* gb  = (float*)d_ws + T;
    u16*   qt2 = (u16*)(gb + T);
    u16*   kt2 = qt2 + 2 * T;
    u16*   vth = kt2 + 2 * T;
    u16*   vtl = vth + T;

    prep_w       <<<256,  256, 0, stream>>>(wq, wk, wv, wg, wTh, wTl);
    lnproj_kernel<<<1024, 512, 0, stream>>>(z, lnw, lnb, wTh, wTl,
                                            qt2, kt2, vth, vtl, gb);
    attn_kernel  <<<2048, 512, 0, stream>>>(qt2, kt2, vth, vtl, gb, go);
    out_kernel   <<<512,  256, 0, stream>>>(go, wo, (float*)d_out);
}

// Round 13
// 155.469 us; speedup vs baseline: 1.0494x; 1.0086x over previous
//
#include <hip/hip_runtime.h>

// TriangleAttentionStartingNode  (B=1, S=256, C=128, H=4, D=32)
//
// Pipeline:
//   K0 prep_w:  {wq,wk,wv,wg} -> wT split-bf16 [n=512][k=128] hi/lo (q-scale folded)
//   K1 lnproj:  (round-10 version, known-good) 1024 blk x 512 thr, block =
//               64 rows x 512 cols. Fused LN -> split-bf16 -> swizzled LDS ->
//               MFMA (A=W^T, B=zn^T, 3 split terms) -> direct scatter epilogue:
//                 qt2: [jh][i][32hi|32lo]  kt2: [jh][k][32hi|32lo]
//                 vth/vtl: [jh][d][k=256]  gb: fp32 sigmoid [row][128]
//   K2 attn:    512 thr = 8 waves x 16 q-rows; 2 blocks per (j,h); K/V in
//               swizzled LDS; swapped QK^T (split x3), in-register softmax,
//               shfl P relayout (P-hi only), PV vs split V; gated output
//               packed as split-bf16 u32 (hi | lo<<16) -> go2
//   K3 out:     NEW: MFMA split-bf16 GEMM. Phase A: wo -> swizzled transposed
//               LDS -> per-lane W fragments (registers). Phase B: go2 unpacked
//               into swizzled hi/lo LDS. 3-term split MFMA, float4 epilogue.
//
// wb skipped: bias constant along softmax axis k -> cancels exactly.
// Round-12 note: the per-matrix LDS-restaged lnproj epilogue raised absmax
// 0.0039 -> 0.0115 (cause not isolated). Reverted to round-10 lnproj.

#define NROWS 65536   // S*S

typedef unsigned short u16;
typedef unsigned int   u32;
typedef __attribute__((ext_vector_type(8))) short short8;
typedef __attribute__((ext_vector_type(4))) float f32x4;
typedef __attribute__((ext_vector_type(4))) u32   u32x4;
typedef __attribute__((ext_vector_type(4))) u16   u16x4;
typedef __attribute__((ext_vector_type(8))) u16   u16x8;   // 16 B

__device__ __forceinline__ u16 f2bf(float x) {            // fp32 -> bf16 RNE
    u32 u = __builtin_bit_cast(u32, x);
    return (u16)((u + 0x7fffu + ((u >> 16) & 1u)) >> 16);
}
__device__ __forceinline__ float bf2f(u16 h) {
    u32 u = (u32)h << 16;
    return __builtin_bit_cast(float, u);
}

// ------------------------------------------------- K0: weight transpose+split
__global__ __launch_bounds__(256) void prep_w(const float* __restrict__ wq,
                                              const float* __restrict__ wk,
                                              const float* __restrict__ wv,
                                              const float* __restrict__ wg,
                                              u16* __restrict__ wTh,
                                              u16* __restrict__ wTl)
{
    const int gid = blockIdx.x * 256 + threadIdx.x;   // 65536
    const int k = gid >> 9, n = gid & 511;
    const float* Wm = (n < 128) ? wq : (n < 256) ? wk : (n < 384) ? wv : wg;
    float f = Wm[k * 128 + (n & 127)];
    if (n < 128) f *= 0.17677669529663687f;           // 1/sqrt(D) into q
    const u16 h = f2bf(f);
    wTh[n * 128 + k] = h;
    wTl[n * 128 + k] = f2bf(f - bf2f(h));
}

// ------------------------------------------------- K1: fused LN + projection
// 1024 blocks x 512 threads (8 waves). Block owns 64 zn rows, all 512 outputs.
__global__ __launch_bounds__(512) void lnproj_kernel(const float* __restrict__ z,
                                                     const float* __restrict__ lnw,
                                                     const float* __restrict__ lnb,
                                                     const u16* __restrict__ wTh,
                                                     const u16* __restrict__ wTl,
                                                     u16* __restrict__ qt2,
                                                     u16* __restrict__ kt2,
                                                     u16* __restrict__ vth,
                                                     u16* __restrict__ vtl,
                                                     float* __restrict__ gb)
{
    const int row0 = blockIdx.x * 64;
    const int tid  = threadIdx.x;

    __shared__ __align__(16) u16 Ah[8192];   // 16 KB: [64 rows][16 slots x 8 u16]
    __shared__ __align__(16) u16 Al[8192];

    // ---- LN + split + stage (32 lanes per row; 16 rows/pass x 4) ----
    {
        const int c4 = (tid & 31) * 4;                 // col, 0..124
        const float4 w4 = *(const float4*)(lnw + c4);
        const float4 b4 = *(const float4*)(lnb + c4);
        #pragma unroll
        for (int it = 0; it < 4; ++it) {
            const int row = it * 16 + (tid >> 5);
            const float4 v = *(const float4*)(z + (size_t)(row0 + row) * 128 + c4);
            float s  = v.x + v.y + v.z + v.w;
            float ss = v.x * v.x + v.y * v.y + v.z * v.z + v.w * v.w;
            #pragma unroll
            for (int off = 16; off > 0; off >>= 1) {
                s  += __shfl_xor(s,  off);
                ss += __shfl_xor(ss, off);
            }
            const float mu  = s * (1.0f / 128.0f);
            const float var = ss * (1.0f / 128.0f) - mu * mu;
            const float rs  = rsqrtf(var + 1e-5f);
            float o[4] = {(v.x - mu) * rs * w4.x + b4.x,
                          (v.y - mu) * rs * w4.y + b4.y,
                          (v.z - mu) * rs * w4.z + b4.z,
                          (v.w - mu) * rs * w4.w + b4.w};
            u16x4 hi, lo;
            #pragma unroll
            for (int c = 0; c < 4; ++c) {
                const u16 hx = f2bf(o[c]);
                hi[c] = hx;
                lo[c] = f2bf(o[c] - bf2f(hx));
            }
            const int slot = c4 >> 3, half = (c4 >> 2) & 1;
            const int phys = slot ^ (row & 15);
            *(u16x4*)&Ah[row * 128 + phys * 8 + half * 4] = hi;
            *(u16x4*)&Al[row * 128 + phys * 8 + half * 4] = lo;
        }
    }
    __syncthreads();

    // ---- MFMA: 8 waves, wave tile 64(n) x 64(m) ----
    const int w    = tid >> 6;          // n-tile group, 0..7
    const int lane = tid & 63;
    const int g    = lane >> 4;
    const int qc   = lane & 15;

    f32x4 acc[4][4];   // [nt][mt]
    #pragma unroll
    for (int a = 0; a < 4; ++a)
        #pragma unroll
        for (int b = 0; b < 4; ++b) acc[a][b] = (f32x4){0.f, 0.f, 0.f, 0.f};

    #pragma unroll
    for (int kc = 0; kc < 4; ++kc) {
        short8 bh[4], bl[4];
        #pragma unroll
        for (int mt = 0; mt < 4; ++mt) {
            const int row  = mt * 16 + qc;
            const int phys = (kc * 4 + g) ^ (row & 15);
            bh[mt] = *(const short8*)&Ah[row * 128 + phys * 8];
            bl[mt] = *(const short8*)&Al[row * 128 + phys * 8];
        }
        #pragma unroll
        for (int nt = 0; nt < 4; ++nt) {
            const int n_row = w * 64 + nt * 16 + qc;
            const short8 ah = *(const short8*)(wTh + (size_t)n_row * 128 + kc * 32 + g * 8);
            const short8 al = *(const short8*)(wTl + (size_t)n_row * 128 + kc * 32 + g * 8);
            #pragma unroll
            for (int mt = 0; mt < 4; ++mt) {
                acc[nt][mt] = __builtin_amdgcn_mfma_f32_16x16x32_bf16(ah, bh[mt], acc[nt][mt], 0, 0, 0);
                acc[nt][mt] = __builtin_amdgcn_mfma_f32_16x16x32_bf16(ah, bl[mt], acc[nt][mt], 0, 0, 0);
                acc[nt][mt] = __builtin_amdgcn_mfma_f32_16x16x32_bf16(al, bh[mt], acc[nt][mt], 0, 0, 0);
            }
        }
    }

    // ---- epilogue: lane holds 4 consecutive n for one m; direct scatter ----
    #pragma unroll
    for (int nt = 0; nt < 4; ++nt) {
        const int nb  = w * 64 + nt * 16 + g * 4;      // 0..508
        const int mat = nb >> 7;                       // 0..3 (wave-uniform)
        const int nn  = nb & 127;
        const int h   = nn >> 5, d0 = nn & 31;
        #pragma unroll
        for (int mt = 0; mt < 4; ++mt) {
            const int m = row0 + mt * 16 + qc;         // global zn row
            const f32x4 a = acc[nt][mt];
            if (mat == 3) {
                float4 sg;
                sg.x = 1.0f / (1.0f + __expf(-a[0]));
                sg.y = 1.0f / (1.0f + __expf(-a[1]));
                sg.z = 1.0f / (1.0f + __expf(-a[2]));
                sg.w = 1.0f / (1.0f + __expf(-a[3]));
                *(float4*)(gb + (size_t)m * 128 + nn) = sg;
            } else if (mat == 2) {
                const int j = m >> 8, kk = m & 255;
                #pragma unroll
                for (int r = 0; r < 4; ++r) {
                    const u16 hx = f2bf(a[r]);
                    const size_t idx = ((size_t)(j * 4 + h) * 32 + d0 + r) * 256 + kk;
                    vth[idx] = hx;
                    vtl[idx] = f2bf(a[r] - bf2f(hx));
                }
            } else {
                u16x4 hi, lo;
                #pragma unroll
                for (int c = 0; c < 4; ++c) {
                    const u16 hx = f2bf(a[c]);
                    hi[c] = hx;
                    lo[c] = f2bf(a[c] - bf2f(hx));
                }
                u16* dst;
                if (mat == 0) {
                    const int i = m >> 8, j = m & 255;
                    dst = qt2 + ((size_t)(j * 4 + h) * 256 + i) * 64 + d0;
                } else {
                    const int j = m >> 8, kk = m & 255;
                    dst = kt2 + ((size_t)(j * 4 + h) * 256 + kk) * 64 + d0;
                }
                *(u16x4*)dst        = hi;
                *(u16x4*)(dst + 32) = lo;
            }
        }
    }
}

// ---------------------------------------------------------- K2: MFMA attention
// Grid 2048: block = (jh, i-half). 512 threads = 8 waves x 16 q-rows.
// Output: go2 packed split-bf16 (hi | lo<<16) per element.
__global__ __launch_bounds__(512) void attn_kernel(const u16* __restrict__ qt2,
                                                   const u16* __restrict__ kt2,
                                                   const u16* __restrict__ vth,
                                                   const u16* __restrict__ vtl,
                                                   const float* __restrict__ gb,
                                                   u32* __restrict__ go2)
{
    const int blk  = blockIdx.x;
    const int jh   = blk >> 1;
    const int tid  = threadIdx.x;
    const int q0   = (blk & 1) * 128 + (tid >> 6) * 16;
    const int lane = tid & 63;
    const int g    = lane >> 4;
    const int qc   = lane & 15;

    __shared__ u16 Ks[16384];    // 32 KB: [256 rows][8 slots x 8 u16], swizzled
    __shared__ u16 Vs[16384];    // 32 KB: vth [32][32 slots] then vtl, swizzled

    // ---- stage K/V into LDS (16B chunks, swizzle on write) ----
    {
        const u16* kg = kt2 + (size_t)jh * 16384;
        #pragma unroll
        for (int it = 0; it < 4; ++it) {
            const int t   = it * 512 + tid;         // 2048 chunks of 8 u16
            const int row = t >> 3, c = t & 7;
            const int dc  = c ^ (row & 7);
            *(u16x8*)&Ks[row * 64 + dc * 8] = *(const u16x8*)(kg + t * 8);
        }
        const u16* vhg = vth + (size_t)jh * 8192;
        const u16* vlg = vtl + (size_t)jh * 8192;
        #pragma unroll
        for (int it = 0; it < 2; ++it) {
            const int t   = it * 512 + tid;         // 1024 chunks
            const int row = t >> 5, c = t & 31;
            const int dc  = (c & 24) | ((c & 7) ^ (row & 7));
            *(u16x8*)&Vs[row * 256 + dc * 8] = *(const u16x8*)(vhg + t * 8);
        }
        #pragma unroll
        for (int it = 0; it < 2; ++it) {
            const int t   = it * 512 + tid;
            const int row = t >> 5, c = t & 31;
            const int dc  = (c & 24) | ((c & 7) ^ (row & 7));
            *(u16x8*)&Vs[8192 + row * 256 + dc * 8] = *(const u16x8*)(vlg + t * 8);
        }
    }

    // Q B-fragments from global (coalesced)
    const u16* qrow = qt2 + ((size_t)jh * 256 + q0 + qc) * 64;
    const short8 bqh = *(const short8*)(qrow + g * 8);
    const short8 bql = *(const short8*)(qrow + 32 + g * 8);

    __syncthreads();

    // ---- QK^T: 16 key-tiles x 3 split terms, K from swizzled LDS ----
    f32x4 st[16];
    #pragma unroll
    for (int t = 0; t < 16; ++t) st[t] = (f32x4){0.f, 0.f, 0.f, 0.f};

    const int slotH = (g ^ (qc & 7)) * 8;
    #pragma unroll
    for (int kt = 0; kt < 16; ++kt) {
        const int rbase = (kt * 16 + qc) * 64;
        const short8 ah = *(const short8*)&Ks[rbase + slotH];
        const short8 al = *(const short8*)&Ks[rbase + (slotH ^ 32)];
        st[kt] = __builtin_amdgcn_mfma_f32_16x16x32_bf16(ah, bqh, st[kt], 0, 0, 0);
        st[kt] = __builtin_amdgcn_mfma_f32_16x16x32_bf16(ah, bql, st[kt], 0, 0, 0);
        st[kt] = __builtin_amdgcn_mfma_f32_16x16x32_bf16(al, bqh, st[kt], 0, 0, 0);
    }

    // ---- softmax over 256 keys for q = qc ----
    float m = -1e30f;
    #pragma unroll
    for (int t = 0; t < 16; ++t)
        #pragma unroll
        for (int r = 0; r < 4; ++r) m = fmaxf(m, st[t][r]);
    m = fmaxf(m, __shfl_xor(m, 16));
    m = fmaxf(m, __shfl_xor(m, 32));

    float l = 0.0f;
    #pragma unroll
    for (int t = 0; t < 16; ++t)
        #pragma unroll
        for (int r = 0; r < 4; ++r) {
            const float p = __expf(st[t][r] - m);
            st[t][r] = p;
            l += p;
        }
    l += __shfl_xor(l, 16);
    l += __shfl_xor(l, 32);
    const float inv = 1.0f / l;
    #pragma unroll
    for (int t = 0; t < 16; ++t)
        #pragma unroll
        for (int r = 0; r < 4; ++r) st[t][r] *= inv;

    // ---- PV: P-hi relayout via shfl, V (hi+lo) from swizzled LDS ----
    f32x4 o0 = (f32x4){0.f, 0.f, 0.f, 0.f};
    f32x4 o1 = (f32x4){0.f, 0.f, 0.f, 0.f};
    const int  slA   = qc + 16 * (2 * (g & 1));
    const int  slB   = slA + 16;
    const bool upper = (g >> 1) != 0;

    #pragma unroll
    for (int kc = 0; kc < 8; ++kc) {
        u32 pkh[2][2];
        #pragma unroll
        for (int tt = 0; tt < 2; ++tt)
            #pragma unroll
            for (int u = 0; u < 2; ++u) {
                const float x = st[2 * kc + tt][2 * u];
                const float y = st[2 * kc + tt][2 * u + 1];
                pkh[tt][u] = (u32)f2bf(x) | ((u32)f2bf(y) << 16);
            }
        u32x4 AH;
        #pragma unroll
        for (int j = 0; j < 4; ++j) {
            const int u  = j & 1;
            const int sl = (j < 2) ? slA : slB;
            const u32 h0 = (u32)__shfl((int)pkh[0][u], sl);
            const u32 h1 = (u32)__shfl((int)pkh[1][u], sl);
            AH[j] = upper ? h1 : h0;
        }
        const short8 pah = __builtin_bit_cast(short8, AH);

        const int vc    = (((kc & 1) * 4 + g) ^ (qc & 7));
        const int vslot = ((kc >> 1) * 8 + vc) * 8;
        const short8 b0h = *(const short8*)&Vs[        qc * 256 + vslot];
        const short8 b0l = *(const short8*)&Vs[8192 +  qc * 256 + vslot];
        const short8 b1h = *(const short8*)&Vs[       (16 + qc) * 256 + vslot];
        const short8 b1l = *(const short8*)&Vs[8192 + (16 + qc) * 256 + vslot];
        o0 = __builtin_amdgcn_mfma_f32_16x16x32_bf16(pah, b0h, o0, 0, 0, 0);
        o0 = __builtin_amdgcn_mfma_f32_16x16x32_bf16(pah, b0l, o0, 0, 0, 0);
        o1 = __builtin_amdgcn_mfma_f32_16x16x32_bf16(pah, b1h, o1, 0, 0, 0);
        o1 = __builtin_amdgcn_mfma_f32_16x16x32_bf16(pah, b1l, o1, 0, 0, 0);
    }

    // ---- epilogue: gate, split to bf16, pack, store ----
    const int jj = jh >> 2, h = jh & 3;
    #pragma unroll
    for (int r = 0; r < 4; ++r) {
        const int qg = q0 + g * 4 + r;
        const size_t base = ((size_t)qg * 256 + jj) * 128 + h * 32 + qc;
        {
            const float x = gb[base] * o0[r];
            const u16 hh = f2bf(x);
            go2[base] = (u32)hh | ((u32)f2bf(x - bf2f(hh)) << 16);
        }
        {
            const float x = gb[base + 16] * o1[r];
            const u16 hh = f2bf(x);
            go2[base + 16] = (u32)hh | ((u32)f2bf(x - bf2f(hh)) << 16);
        }
    }
}

// ------------------------------------------------------- K3: output MFMA GEMM
// 512 blocks x 512 threads (8 waves). Block = 128 rows x 128 cols.
// Phase A: wo -> swizzled transposed fp32 LDS -> per-lane split W fragments.
// Phase B: go2 unpacked into swizzled hi/lo LDS; 3-term split MFMA.
__global__ __launch_bounds__(512) void out_kernel(const u32* __restrict__ go2,
                                                  const float* __restrict__ wo,
                                                  float* __restrict__ out)
{
    const int row0 = blockIdx.x * 128;
    const int tid  = threadIdx.x;

    __shared__ __align__(16) u16 BUF[32768];   // 64 KB, two-phase reuse

    const int w    = tid >> 6;
    const int lane = tid & 63;
    const int g    = lane >> 4;
    const int qc   = lane & 15;
    const int wn   = w & 3;        // n-group (32 cols)
    const int wm   = w >> 2;       // m-half  (64 rows)

    // ---- phase A: wo -> swizzled transposed LDS -> W fragments in regs ----
    short8 wfh[4][2], wfl[4][2];
    {
        float* WT = (float*)BUF;   // logical [n=128][k=128], slot-swizzled
        #pragma unroll
        for (int p = 0; p < 8; ++p) {
            const int idx = p * 512 + tid;        // 4096 float4 of wo
            const int k = idx >> 5, n4 = (idx & 31) * 4;
            const float4 v = *(const float4*)(wo + k * 128 + n4);
            const int slot = k >> 3, ins = k & 7;
            #pragma unroll
            for (int c = 0; c < 4; ++c) {
                const int n = n4 + c;
                WT[n * 128 + ((slot ^ (n & 15)) * 8) + ins] =
                    (c == 0) ? v.x : (c == 1) ? v.y : (c == 2) ? v.z : v.w;
            }
        }
        __syncthreads();
        #pragma unroll
        for (int kc = 0; kc < 4; ++kc)
            #pragma unroll
            for (int nt = 0; nt < 2; ++nt) {
                const int n_row = wn * 32 + nt * 16 + qc;
                const int phys  = (kc * 4 + g) ^ (n_row & 15);
                const float4 v0 = *(const float4*)&WT[n_row * 128 + phys * 8];
                const float4 v1 = *(const float4*)&WT[n_row * 128 + phys * 8 + 4];
                const float vv[8] = {v0.x, v0.y, v0.z, v0.w, v1.x, v1.y, v1.z, v1.w};
                short8 sh, sl;
                #pragma unroll
                for (int e = 0; e < 8; ++e) {
                    const u16 hx = f2bf(vv[e]);
                    sh[e] = (short)hx;
                    sl[e] = (short)f2bf(vv[e] - bf2f(hx));
                }
                wfh[kc][nt] = sh;
                wfl[kc][nt] = sl;
            }
        __syncthreads();   // WT dead
    }

    // ---- phase B: stage go2 (unpack hi/lo) into swizzled LDS ----
    u16* Ah = BUF;            // [128 rows][16 slots x 8]
    u16* Al = BUF + 16384;
    {
        #pragma unroll
        for (int p = 0; p < 4; ++p) {
            const int t   = p * 512 + tid;        // 2048 chunks of 8 channels
            const int row = t >> 4, c8 = t & 15;
            const u32* src = go2 + (size_t)(row0 + row) * 128 + c8 * 8;
            const u32x4 p0 = *(const u32x4*)src;
            const u32x4 p1 = *(const u32x4*)(src + 4);
            u16x4 h0, l0, h1, l1;
            #pragma unroll
            for (int c = 0; c < 4; ++c) {
                h0[c] = (u16)(p0[c] & 0xffffu); l0[c] = (u16)(p0[c] >> 16);
                h1[c] = (u16)(p1[c] & 0xffffu); l1[c] = (u16)(p1[c] >> 16);
            }
            const int phys = c8 ^ (row & 15);
            *(u16x4*)&Ah[row * 128 + phys * 8]     = h0;
            *(u16x4*)&Ah[row * 128 + phys * 8 + 4] = h1;
            *(u16x4*)&Al[row * 128 + phys * 8]     = l0;
            *(u16x4*)&Al[row * 128 + phys * 8 + 4] = l1;
        }
    }
    __syncthreads();

    // ---- MFMA: wave = 32 n x 64 m, acc[2][4] ----
    f32x4 acc[2][4];
    #pragma unroll
    for (int a = 0; a < 2; ++a)
        #pragma unroll
        for (int b = 0; b < 4; ++b) acc[a][b] = (f32x4){0.f, 0.f, 0.f, 0.f};

    #pragma unroll
    for (int kc = 0; kc < 4; ++kc) {
        short8 bh[4], bl[4];
        #pragma unroll
        for (int mt = 0; mt < 4; ++mt) {
            const int row  = wm * 64 + mt * 16 + qc;
            const int phys = (kc * 4 + g) ^ (row & 15);
            bh[mt] = *(const short8*)&Ah[row * 128 + phys * 8];
            bl[mt] = *(const short8*)&Al[row * 128 + phys * 8];
        }
        #pragma unroll
        for (int nt = 0; nt < 2; ++nt)
            #pragma unroll
            for (int mt = 0; mt < 4; ++mt) {
                acc[nt][mt] = __builtin_amdgcn_mfma_f32_16x16x32_bf16(wfh[kc][nt], bh[mt], acc[nt][mt], 0, 0, 0);
                acc[nt][mt] = __builtin_amdgcn_mfma_f32_16x16x32_bf16(wfh[kc][nt], bl[mt], acc[nt][mt], 0, 0, 0);
                acc[nt][mt] = __builtin_amdgcn_mfma_f32_16x16x32_bf16(wfl[kc][nt], bh[mt], acc[nt][mt], 0, 0, 0);
            }
    }

    // ---- epilogue: lane holds 4 consecutive n for one m ----
    #pragma unroll
    for (int nt = 0; nt < 2; ++nt) {
        const int n = wn * 32 + nt * 16 + g * 4;
        #pragma unroll
        for (int mt = 0; mt < 4; ++mt) {
            const int m = row0 + wm * 64 + mt * 16 + qc;
            float4 v;
            v.x = acc[nt][mt][0]; v.y = acc[nt][mt][1];
            v.z = acc[nt][mt][2]; v.w = acc[nt][mt][3];
            *(float4*)(out + (size_t)m * 128 + n) = v;
        }
    }
}

// ----------------------------------------------------------------- launch
extern "C" void kernel_launch(void* const* d_in, const int* in_sizes, int n_in,
                              void* d_out, int out_size, void* d_ws, size_t ws_size,
                              hipStream_t stream)
{
    const float* z   = (const float*)d_in[0];
    const float* lnw = (const float*)d_in[1];
    const float* lnb = (const float*)d_in[2];
    const float* wq  = (const float*)d_in[3];
    const float* wk  = (const float*)d_in[4];
    const float* wv  = (const float*)d_in[5];
    // d_in[6] = wb : unused (constant along softmax axis -> cancels)
    const float* wg  = (const float*)d_in[7];
    const float* wo  = (const float*)d_in[8];

    const size_t T = (size_t)NROWS * 128;       // 8,388,608 elements
    u32*   go2 = (u32*)d_ws;                    // also hosts wT (liveness disjoint)
    u16*   wTh = (u16*)d_ws;
    u16*   wTl = wTh + 512 * 128;
    float* gb  = (float*)d_ws + T;
    u16*   qt2 = (u16*)(gb + T);
    u16*   kt2 = qt2 + 2 * T;
    u16*   vth = kt2 + 2 * T;
    u16*   vtl = vth + T;

    prep_w       <<<256,  256, 0, stream>>>(wq, wk, wv, wg, wTh, wTl);
    lnproj_kernel<<<1024, 512, 0, stream>>>(z, lnw, lnb, wTh, wTl,
                                            qt2, kt2, vth, vtl, gb);
    attn_kernel  <<<2048, 512, 0, stream>>>(qt2, kt2, vth, vtl, gb, go2);
    out_kernel   <<<512,  512, 0, stream>>>(go2, wo, (float*)d_out);
}